// Round 8
// baseline (203.932 us; speedup 1.0000x reference)
//
#include <hip/hip_runtime.h>

constexpr int NPAIR = 780;
constexpr int BD = 512;

// ---- fused-kernel LDS layout (floats) ----
constexpr int OFF_ZT = 0;            // Zt[32][40] stride 40            1280
constexpr int OFF_A  = 1280;         // h[40][132]=5280 | Ut[3][32][40]=3840
constexpr int UTP    = 1280;         // Ut plane stride
constexpr int OFF_BT = 5120;         // bilT[5][780]=3900 (h tail overlaps; h dead by then)
constexpr int OFF_HW = 9020;         // head weights 744
constexpr int SH_TOT = 9764;         // 39056 B -> 4 blocks/CU (32 waves at BD=512)

// =================== prep: cluster head + wsym + sigma + head-weight table ===================
__global__ __launch_bounds__(256) void prep_kernel(
    const float* __restrict__ eta,
    const float* __restrict__ cW1, const float* __restrict__ cb1,
    const float* __restrict__ cW2, const float* __restrict__ cb2,
    const float* __restrict__ cWs, const float* __restrict__ cbs,
    const float* __restrict__ bond, const float* __restrict__ lsig,
    const float* __restrict__ bW1, const float* __restrict__ bb1,
    const float* __restrict__ bW2, const float* __restrict__ bb2,
    const float* __restrict__ bWs, const float* __restrict__ bbs,
    float* __restrict__ log_pi, float* __restrict__ wsym,
    float* __restrict__ sigma, float* __restrict__ hwg)
{
  if (blockIdx.x < 256) {
    const int lane = threadIdx.x & 63, wid = threadIdx.x >> 6;
    const int row = blockIdx.x * 4 + wid;
    __shared__ __align__(16) float etas[4][64];
    __shared__ __align__(16) float hs[4][128];
    etas[wid][lane] = eta[row * 64 + lane];
    __syncthreads();
    float a0 = cb1[lane], a1 = cb1[lane + 64];
    for (int d = 0; d < 64; ++d) {
      float ed = etas[wid][d];
      a0 += ed * cW1[d * 128 + lane];
      a1 += ed * cW1[d * 128 + lane + 64];
    }
    hs[wid][lane] = fmaxf(a0, 0.f);
    hs[wid][lane + 64] = fmaxf(a1, 0.f);
    __syncthreads();
    if (lane < 32) {
      float x = cb2[lane] + cbs[lane];
      for (int j = 0; j < 128; ++j) x += hs[wid][j] * cW2[j * 32 + lane];
      for (int d = 0; d < 64; ++d) x += etas[wid][d] * cWs[d * 32 + lane];
      float m = x;
      for (int off = 16; off; off >>= 1) m = fmaxf(m, __shfl_xor(m, off));
      float e = __expf(x - m);
      float s = e;
      for (int off = 16; off; off >>= 1) s += __shfl_xor(s, off);
      log_pi[row * 32 + lane] = (x - m) - __logf(s);
    }
  } else {
    const int e = (blockIdx.x - 256) * 256 + threadIdx.x;
    if (e < 5120) {
      const int t = e >> 10, r = e & 1023, c = r >> 5, d = r & 31;
      wsym[e] = 0.5f * (bond[e] + bond[t * 1024 + d * 32 + c]);
    } else if (e < 6144) {
      const int q = e - 5120;
      sigma[q] = __expf(fminf(fmaxf(lsig[q], -20.f), 30.f));
    } else if (e < 6888) {
      const int idx = e - 6144;
      float v;
      if (idx < 320) v = bW1[idx];
      else if (idx < 384) v = bb1[idx - 320];
      else if (idx < 704) { int qq = idx - 384; int t2 = qq >> 6, j = qq & 63; v = bW2[j * 5 + t2]; }
      else if (idx < 709) v = bb2[idx - 704];
      else if (idx < 734) v = bWs[idx - 709];
      else v = bbs[idx - 734];
      hwg[idx] = v;
    }
  }
}

// =================== fused per-molecule kernel, 512 threads ===================
__global__ __launch_bounds__(BD, 8) void fused_kernel(
    const float* __restrict__ log_pi, const float* __restrict__ gumbel,
    const float* __restrict__ z_noise,
    const float* __restrict__ means, const float* __restrict__ sigma,
    const float* __restrict__ aW1, const float* __restrict__ ab1,
    const float* __restrict__ aW2, const float* __restrict__ ab2,
    const float* __restrict__ aWs, const float* __restrict__ abs_,
    const float* __restrict__ wsym, const float* __restrict__ hwg,
    float* __restrict__ atom_out, float* __restrict__ edge_out)
{
  __shared__ __align__(16) float S[SH_TOT];
  const int tid = threadIdx.x;
  const int m = blockIdx.x;

  // ---------- phase 1: z sample (tid<40) + head-weight staging (tid>=64) ----------
  if (tid < 40) {
    const int n = m * 40 + tid;
    float lp[32];
    #pragma unroll
    for (int c = 0; c < 32; ++c) lp[c] = log_pi[m * 32 + c];   // uniform -> scalar loads
    float g[32];
    const float4* g4 = (const float4*)(gumbel + (size_t)n * 32);
    #pragma unroll
    for (int q = 0; q < 8; ++q) {
      float4 v = g4[q];
      g[4*q] = v.x; g[4*q+1] = v.y; g[4*q+2] = v.z; g[4*q+3] = v.w;
    }
    int kb = 0; float vb = lp[0] + g[0];
    #pragma unroll
    for (int c = 1; c < 32; ++c) {
      float v = lp[c] + g[c];
      if (v > vb) { vb = v; kb = c; }   // first-index tie-break
    }
    const float4* zn4 = (const float4*)(z_noise + (size_t)n * 32);
    const float4* mk4 = (const float4*)(means + kb * 32);
    const float4* sg4 = (const float4*)(sigma + kb * 32);
    #pragma unroll
    for (int q = 0; q < 8; ++q) {
      float4 zn = zn4[q], mk = mk4[q], sg = sg4[q];
      S[OFF_ZT + (4*q    ) * 40 + tid] = zn.x * sg.x + mk.x;
      S[OFF_ZT + (4*q + 1) * 40 + tid] = zn.y * sg.y + mk.y;
      S[OFF_ZT + (4*q + 2) * 40 + tid] = zn.z * sg.z + mk.z;
      S[OFF_ZT + (4*q + 3) * 40 + tid] = zn.w * sg.w + mk.w;
    }
  } else if (tid >= 64) {
    for (int idx = tid - 64; idx < 744; idx += (BD - 64)) S[OFF_HW + idx] = hwg[idx];
  }
  __syncthreads();

  // ---------- phase 2: atom-h, 4n x 4j tiles -> h[n][j] row-major (stride 132) ----------
  if (tid < 320) {
    const int ng = tid >> 5, jg = tid & 31;
    const int n0 = ng * 4, j0 = jg * 4;
    float acc[4][4];
    #pragma unroll
    for (int a = 0; a < 4; ++a)
      #pragma unroll
      for (int b = 0; b < 4; ++b) acc[a][b] = 0.f;
    #pragma unroll 8
    for (int c = 0; c < 32; ++c) {
      float4 zv = *(const float4*)&S[OFF_ZT + c * 40 + n0];
      float4 wv = *(const float4*)(aW1 + c * 128 + j0);
      acc[0][0] += zv.x * wv.x; acc[0][1] += zv.x * wv.y; acc[0][2] += zv.x * wv.z; acc[0][3] += zv.x * wv.w;
      acc[1][0] += zv.y * wv.x; acc[1][1] += zv.y * wv.y; acc[1][2] += zv.y * wv.z; acc[1][3] += zv.y * wv.w;
      acc[2][0] += zv.z * wv.x; acc[2][1] += zv.z * wv.y; acc[2][2] += zv.z * wv.z; acc[2][3] += zv.z * wv.w;
      acc[3][0] += zv.w * wv.x; acc[3][1] += zv.w * wv.y; acc[3][2] += zv.w * wv.z; acc[3][3] += zv.w * wv.w;
    }
    float4 bv = *(const float4*)(ab1 + j0);
    #pragma unroll
    for (int a = 0; a < 4; ++a) {
      float4 hv;
      hv.x = fmaxf(acc[a][0] + bv.x, 0.f);
      hv.y = fmaxf(acc[a][1] + bv.y, 0.f);
      hv.z = fmaxf(acc[a][2] + bv.z, 0.f);
      hv.w = fmaxf(acc[a][3] + bv.w, 0.f);
      *(float4*)&S[OFF_A + (n0 + a) * 132 + j0] = hv;   // unit-stride b128: conflict-free
    }
  }
  __syncthreads();

  // ---------- phase 3: atom-out, thread = (n, kpair) ----------
  if (tid < 200) {
    const int n = tid / 5, kp = tid - (tid / 5) * 5, k0 = kp * 2;
    float a0 = ab2[k0] + abs_[k0];
    float a1 = ab2[k0 + 1] + abs_[k0 + 1];
    #pragma unroll 8
    for (int c = 0; c < 32; ++c) {
      float zc = S[OFF_ZT + c * 40 + n];
      float2 w = *(const float2*)(aWs + c * 10 + k0);
      a0 += zc * w.x; a1 += zc * w.y;
    }
    #pragma unroll 8
    for (int j = 0; j < 128; ++j) {
      float hv = S[OFF_A + n * 132 + j];
      float2 w = *(const float2*)(aW2 + j * 10 + k0);
      a0 += hv * w.x; a1 += hv * w.y;
    }
    *(float2*)(atom_out + (size_t)m * 400 + n * 10 + k0) = make_float2(a0, a1);
  }
  __syncthreads();   // h dead

  // ---------- phases 4-7: U + bilinear, two t-rounds ----------
  #pragma unroll
  for (int R = 0; R < 2; ++R) {
    const int tbase = (R == 0) ? 0 : 3;
    const int nplanes = (R == 0) ? 3 : 2;
    // U: units (tl, dg, ig) -> Ut[tl][d][i]
    if (tid < nplanes * 80) {
      const int tl = tid / 80, r = tid - tl * 80;
      const int dg = r / 10, ig = r - dg * 10;
      const int d0 = dg * 4, i0 = ig * 4;
      const float* wg = wsym + (tbase + tl) * 1024;
      float acc[4][4];   // [di][ii]
      #pragma unroll
      for (int a = 0; a < 4; ++a)
        #pragma unroll
        for (int b = 0; b < 4; ++b) acc[a][b] = 0.f;
      #pragma unroll 8
      for (int c = 0; c < 32; ++c) {
        float4 zv = *(const float4*)&S[OFF_ZT + c * 40 + i0];
        float4 wv = *(const float4*)(wg + c * 32 + d0);
        acc[0][0] += wv.x * zv.x; acc[0][1] += wv.x * zv.y; acc[0][2] += wv.x * zv.z; acc[0][3] += wv.x * zv.w;
        acc[1][0] += wv.y * zv.x; acc[1][1] += wv.y * zv.y; acc[1][2] += wv.y * zv.z; acc[1][3] += wv.y * zv.w;
        acc[2][0] += wv.z * zv.x; acc[2][1] += wv.z * zv.y; acc[2][2] += wv.z * zv.z; acc[2][3] += wv.z * zv.w;
        acc[3][0] += wv.w * zv.x; acc[3][1] += wv.w * zv.y; acc[3][2] += wv.w * zv.z; acc[3][3] += wv.w * zv.w;
      }
      #pragma unroll
      for (int a = 0; a < 4; ++a)
        *(float4*)&S[OFF_A + tl * UTP + (d0 + a) * 40 + i0] =
            make_float4(acc[a][0], acc[a][1], acc[a][2], acc[a][3]);
    }
    __syncthreads();

    // bilinear: units (tl, triangular 4i x 4j tile)
    if (tid < nplanes * 55) {
      const int tl = tid / 55;
      int q = tid - tl * 55;
      int ig = 0;
      while (q >= 10 - ig) { q -= 10 - ig; ++ig; }
      const int jg = ig + q;
      const int i0 = ig * 4, j0 = jg * 4;
      float acc[4][4];
      #pragma unroll
      for (int a = 0; a < 4; ++a)
        #pragma unroll
        for (int b = 0; b < 4; ++b) acc[a][b] = 0.f;
      #pragma unroll 8
      for (int d = 0; d < 32; ++d) {
        float4 uv = *(const float4*)&S[OFF_A + tl * UTP + d * 40 + i0];
        float4 zv = *(const float4*)&S[OFF_ZT + d * 40 + j0];
        acc[0][0] += uv.x * zv.x; acc[0][1] += uv.x * zv.y; acc[0][2] += uv.x * zv.z; acc[0][3] += uv.x * zv.w;
        acc[1][0] += uv.y * zv.x; acc[1][1] += uv.y * zv.y; acc[1][2] += uv.y * zv.z; acc[1][3] += uv.y * zv.w;
        acc[2][0] += uv.z * zv.x; acc[2][1] += uv.z * zv.y; acc[2][2] += uv.z * zv.z; acc[2][3] += uv.z * zv.w;
        acc[3][0] += uv.w * zv.x; acc[3][1] += uv.w * zv.y; acc[3][2] += uv.w * zv.z; acc[3][3] += uv.w * zv.w;
      }
      const int tg = tbase + tl;
      #pragma unroll
      for (int a = 0; a < 4; ++a) {
        const int i = i0 + a;
        #pragma unroll
        for (int b = 0; b < 4; ++b) {
          const int j = j0 + b;
          if (i < j) {
            const int p = i * (79 - i) / 2 + (j - i - 1);
            S[OFF_BT + tg * 780 + p] = acc[a][b];
          }
        }
      }
    }
    __syncthreads();
  }

  // ---------- phase 8: edge head, 2 pair-slots per thread (512 + 268 = 780) ----------
  const float* w1h = &S[OFF_HW];
  const float* b1h = &S[OFF_HW + 320];
  const float* w2t = &S[OFF_HW + 384];
  const float* b2h = &S[OFF_HW + 704];
  const float* wsh = &S[OFF_HW + 709];
  const float* bsh = &S[OFF_HW + 734];

  const int p1 = BD + tid;
  const bool v1 = (p1 < NPAIR);
  const int pc[2] = { tid, v1 ? p1 : 0 };

  float bil5[2][5], lg[2][5];
  #pragma unroll
  for (int s = 0; s < 2; ++s) {
    #pragma unroll
    for (int t = 0; t < 5; ++t) bil5[s][t] = S[OFF_BT + t * 780 + pc[s]];
    #pragma unroll
    for (int t2 = 0; t2 < 5; ++t2) {
      float a = b2h[t2] + bsh[t2];
      #pragma unroll
      for (int t = 0; t < 5; ++t) a += bil5[s][t] * wsh[t * 5 + t2];
      lg[s][t2] = a;
    }
  }
  for (int j4 = 0; j4 < 16; ++j4) {
    float4 bb = ((const float4*)b1h)[j4];
    float4 h[2];
    h[0] = bb; h[1] = bb;
    #pragma unroll
    for (int t = 0; t < 5; ++t) {
      float4 w1 = ((const float4*)(w1h + t * 64))[j4];
      #pragma unroll
      for (int s = 0; s < 2; ++s) {
        float bt = bil5[s][t];
        h[s].x += bt * w1.x; h[s].y += bt * w1.y; h[s].z += bt * w1.z; h[s].w += bt * w1.w;
      }
    }
    #pragma unroll
    for (int s = 0; s < 2; ++s) {
      h[s].x = fmaxf(h[s].x, 0.f); h[s].y = fmaxf(h[s].y, 0.f);
      h[s].z = fmaxf(h[s].z, 0.f); h[s].w = fmaxf(h[s].w, 0.f);
    }
    #pragma unroll
    for (int t2 = 0; t2 < 5; ++t2) {
      float4 w2 = ((const float4*)(w2t + t2 * 64))[j4];
      #pragma unroll
      for (int s = 0; s < 2; ++s)
        lg[s][t2] += h[s].x * w2.x + h[s].y * w2.y + h[s].z * w2.z + h[s].w * w2.w;
    }
  }
  #pragma unroll
  for (int s = 0; s < 2; ++s) {
    if (s == 1 && !v1) continue;
    float mx = lg[s][0];
    #pragma unroll
    for (int t2 = 1; t2 < 5; ++t2) mx = fmaxf(mx, lg[s][t2]);
    float e[5], sum = 0.f;
    #pragma unroll
    for (int t2 = 0; t2 < 5; ++t2) { e[t2] = __expf(lg[s][t2] - mx); sum += e[t2]; }
    float inv = 1.f / sum;
    float* outp = edge_out + ((size_t)m * NPAIR + pc[s]) * 5;
    #pragma unroll
    for (int t2 = 0; t2 < 5; ++t2) outp[t2] = e[t2] * inv;
  }
}

extern "C" void kernel_launch(void* const* d_in, const int* in_sizes, int n_in,
                              void* d_out, int out_size, void* d_ws, size_t ws_size,
                              hipStream_t stream) {
  const float* eta    = (const float*)d_in[0];
  const float* gumbel = (const float*)d_in[1];
  const float* z_noise= (const float*)d_in[2];
  const float* cW1 = (const float*)d_in[3];
  const float* cb1 = (const float*)d_in[4];
  const float* cW2 = (const float*)d_in[5];
  const float* cb2 = (const float*)d_in[6];
  const float* cWs = (const float*)d_in[7];
  const float* cbs = (const float*)d_in[8];
  const float* means = (const float*)d_in[9];
  const float* lsig  = (const float*)d_in[10];
  const float* aW1 = (const float*)d_in[11];
  const float* ab1 = (const float*)d_in[12];
  const float* aW2 = (const float*)d_in[13];
  const float* ab2 = (const float*)d_in[14];
  const float* aWs = (const float*)d_in[15];
  const float* abs_= (const float*)d_in[16];
  const float* bond= (const float*)d_in[17];
  const float* bW1 = (const float*)d_in[18];
  const float* bb1 = (const float*)d_in[19];
  const float* bW2 = (const float*)d_in[20];
  const float* bb2 = (const float*)d_in[21];
  const float* bWs = (const float*)d_in[22];
  const float* bbs = (const float*)d_in[23];

  float* wsym   = (float*)d_ws;          // 5120
  float* sigma  = wsym + 5120;           // 1024
  float* hwg    = sigma + 1024;          // 744 (+pad)
  float* log_pi = hwg + 768;             // 1024*32
  float* atom_out = (float*)d_out;                    // 1024*400
  float* edge_out = atom_out + (size_t)1024 * 400;    // 1024*780*5

  prep_kernel<<<284, 256, 0, stream>>>(eta, cW1, cb1, cW2, cb2, cWs, cbs,
                                       bond, lsig, bW1, bb1, bW2, bb2, bWs, bbs,
                                       log_pi, wsym, sigma, hwg);
  fused_kernel<<<1024, BD, 0, stream>>>(log_pi, gumbel, z_noise,
                                        means, sigma, aW1, ab1, aW2, ab2, aWs, abs_,
                                        wsym, hwg, atom_out, edge_out);
}

// Round 9
// 183.035 us; speedup vs baseline: 1.1142x; 1.1142x over previous
//
#include <hip/hip_runtime.h>

constexpr int NPAIR = 780;

// ---- fused-kernel LDS layout (floats) ----
constexpr int OFF_ZT = 0;            // Zt[32][40] stride 40            1280
constexpr int OFF_A  = 1280;         // h[40][132]=5280 | Ut[3][32][40]=3840
constexpr int UTP    = 1280;         // Ut plane stride
constexpr int OFF_BT = 5120;         // bilT[5][780]=3900
constexpr int SH_TOT = 9020;         // 36080 B -> 4 blocks/CU

// =================== prep: cluster head + wsym + sigma + head-weight table ===================
__global__ __launch_bounds__(256) void prep_kernel(
    const float* __restrict__ eta,
    const float* __restrict__ cW1, const float* __restrict__ cb1,
    const float* __restrict__ cW2, const float* __restrict__ cb2,
    const float* __restrict__ cWs, const float* __restrict__ cbs,
    const float* __restrict__ bond, const float* __restrict__ lsig,
    const float* __restrict__ bW1, const float* __restrict__ bb1,
    const float* __restrict__ bW2, const float* __restrict__ bb2,
    const float* __restrict__ bWs, const float* __restrict__ bbs,
    float* __restrict__ log_pi, float* __restrict__ wsym,
    float* __restrict__ sigma, float* __restrict__ hwg)
{
  if (blockIdx.x < 256) {
    const int lane = threadIdx.x & 63, wid = threadIdx.x >> 6;
    const int row = blockIdx.x * 4 + wid;
    __shared__ __align__(16) float etas[4][64];
    __shared__ __align__(16) float hs[4][128];
    etas[wid][lane] = eta[row * 64 + lane];
    __syncthreads();
    float a0 = cb1[lane], a1 = cb1[lane + 64];
    for (int d = 0; d < 64; ++d) {
      float ed = etas[wid][d];
      a0 += ed * cW1[d * 128 + lane];
      a1 += ed * cW1[d * 128 + lane + 64];
    }
    hs[wid][lane] = fmaxf(a0, 0.f);
    hs[wid][lane + 64] = fmaxf(a1, 0.f);
    __syncthreads();
    if (lane < 32) {
      float x = cb2[lane] + cbs[lane];
      for (int j = 0; j < 128; ++j) x += hs[wid][j] * cW2[j * 32 + lane];
      for (int d = 0; d < 64; ++d) x += etas[wid][d] * cWs[d * 32 + lane];
      float m = x;
      for (int off = 16; off; off >>= 1) m = fmaxf(m, __shfl_xor(m, off));
      float e = __expf(x - m);
      float s = e;
      for (int off = 16; off; off >>= 1) s += __shfl_xor(s, off);
      log_pi[row * 32 + lane] = (x - m) - __logf(s);
    }
  } else {
    const int e = (blockIdx.x - 256) * 256 + threadIdx.x;
    if (e < 5120) {
      const int t = e >> 10, r = e & 1023, c = r >> 5, d = r & 31;
      wsym[e] = 0.5f * (bond[e] + bond[t * 1024 + d * 32 + c]);
    } else if (e < 6144) {
      const int q = e - 5120;
      sigma[q] = __expf(fminf(fmaxf(lsig[q], -20.f), 30.f));
    } else if (e < 6888) {
      // hwg: w1h[320]@0, b1h[64]@320, w2t[320]@384 (bW2^T), b2h[5]@704, wsh[25]@709, bsh[5]@734
      const int idx = e - 6144;
      float v;
      if (idx < 320) v = bW1[idx];
      else if (idx < 384) v = bb1[idx - 320];
      else if (idx < 704) { int qq = idx - 384; int t2 = qq >> 6, j = qq & 63; v = bW2[j * 5 + t2]; }
      else if (idx < 709) v = bb2[idx - 704];
      else if (idx < 734) v = bWs[idx - 709];
      else v = bbs[idx - 734];
      hwg[idx] = v;
    }
  }
}

// =================== fused per-molecule kernel, 256 threads (R7 config) ===================
__global__ __launch_bounds__(256, 4) void fused_kernel(
    const float* __restrict__ log_pi, const float* __restrict__ gumbel,
    const float* __restrict__ z_noise,
    const float* __restrict__ means, const float* __restrict__ sigma,
    const float* __restrict__ aW1, const float* __restrict__ ab1,
    const float* __restrict__ aW2, const float* __restrict__ ab2,
    const float* __restrict__ aWs, const float* __restrict__ abs_,
    const float* __restrict__ wsym, const float* __restrict__ hwg,
    float* __restrict__ atom_out, float* __restrict__ edge_out)
{
  __shared__ __align__(16) float S[SH_TOT];
  const int tid = threadIdx.x;
  const int m = blockIdx.x;

  // ---------- phase 1: z sample (tid<40) ----------
  if (tid < 40) {
    const int n = m * 40 + tid;
    float lp[32];
    #pragma unroll
    for (int c = 0; c < 32; ++c) lp[c] = log_pi[m * 32 + c];   // uniform -> scalar loads
    float g[32];
    const float4* g4 = (const float4*)(gumbel + (size_t)n * 32);
    #pragma unroll
    for (int q = 0; q < 8; ++q) {
      float4 v = g4[q];
      g[4*q] = v.x; g[4*q+1] = v.y; g[4*q+2] = v.z; g[4*q+3] = v.w;
    }
    int kb = 0; float vb = lp[0] + g[0];
    #pragma unroll
    for (int c = 1; c < 32; ++c) {
      float v = lp[c] + g[c];
      if (v > vb) { vb = v; kb = c; }   // first-index tie-break
    }
    const float4* zn4 = (const float4*)(z_noise + (size_t)n * 32);
    const float4* mk4 = (const float4*)(means + kb * 32);
    const float4* sg4 = (const float4*)(sigma + kb * 32);
    #pragma unroll
    for (int q = 0; q < 8; ++q) {
      float4 zn = zn4[q], mk = mk4[q], sg = sg4[q];
      S[OFF_ZT + (4*q    ) * 40 + tid] = zn.x * sg.x + mk.x;
      S[OFF_ZT + (4*q + 1) * 40 + tid] = zn.y * sg.y + mk.y;
      S[OFF_ZT + (4*q + 2) * 40 + tid] = zn.z * sg.z + mk.z;
      S[OFF_ZT + (4*q + 3) * 40 + tid] = zn.w * sg.w + mk.w;
    }
  }
  __syncthreads();

  // ---------- phase 2: atom-h, 4n x 4j tiles -> h[n][j] row-major (stride 132) ----------
  for (int u = tid; u < 320; u += 256) {
    const int ng = u >> 5, jg = u & 31;
    const int n0 = ng * 4, j0 = jg * 4;
    float acc[4][4];
    #pragma unroll
    for (int a = 0; a < 4; ++a)
      #pragma unroll
      for (int b = 0; b < 4; ++b) acc[a][b] = 0.f;
    #pragma unroll 8
    for (int c = 0; c < 32; ++c) {
      float4 zv = *(const float4*)&S[OFF_ZT + c * 40 + n0];
      float4 wv = *(const float4*)(aW1 + c * 128 + j0);
      acc[0][0] += zv.x * wv.x; acc[0][1] += zv.x * wv.y; acc[0][2] += zv.x * wv.z; acc[0][3] += zv.x * wv.w;
      acc[1][0] += zv.y * wv.x; acc[1][1] += zv.y * wv.y; acc[1][2] += zv.y * wv.z; acc[1][3] += zv.y * wv.w;
      acc[2][0] += zv.z * wv.x; acc[2][1] += zv.z * wv.y; acc[2][2] += zv.z * wv.z; acc[2][3] += zv.z * wv.w;
      acc[3][0] += zv.w * wv.x; acc[3][1] += zv.w * wv.y; acc[3][2] += zv.w * wv.z; acc[3][3] += zv.w * wv.w;
    }
    float4 bv = *(const float4*)(ab1 + j0);
    #pragma unroll
    for (int a = 0; a < 4; ++a) {
      float4 hv;
      hv.x = fmaxf(acc[a][0] + bv.x, 0.f);
      hv.y = fmaxf(acc[a][1] + bv.y, 0.f);
      hv.z = fmaxf(acc[a][2] + bv.z, 0.f);
      hv.w = fmaxf(acc[a][3] + bv.w, 0.f);
      *(float4*)&S[OFF_A + (n0 + a) * 132 + j0] = hv;   // unit-stride b128 writes
    }
  }
  __syncthreads();

  // ---------- phase 3: atom-out, thread = (n, kpair) ----------
  if (tid < 200) {
    const int n = tid / 5, kp = tid - (tid / 5) * 5, k0 = kp * 2;
    float a0 = ab2[k0] + abs_[k0];
    float a1 = ab2[k0 + 1] + abs_[k0 + 1];
    #pragma unroll 8
    for (int c = 0; c < 32; ++c) {
      float zc = S[OFF_ZT + c * 40 + n];
      float2 w = *(const float2*)(aWs + c * 10 + k0);
      a0 += zc * w.x; a1 += zc * w.y;
    }
    #pragma unroll 8
    for (int j = 0; j < 128; ++j) {
      float hv = S[OFF_A + n * 132 + j];
      float2 w = *(const float2*)(aW2 + j * 10 + k0);
      a0 += hv * w.x; a1 += hv * w.y;
    }
    *(float2*)(atom_out + (size_t)m * 400 + n * 10 + k0) = make_float2(a0, a1);
  }
  __syncthreads();   // h dead

  // ---------- phases 4-7: U + bilinear, two t-rounds ----------
  #pragma unroll
  for (int R = 0; R < 2; ++R) {
    const int tbase = (R == 0) ? 0 : 3;
    const int nplanes = (R == 0) ? 3 : 2;
    // U: units (tl, dg, ig) -> Ut[tl][d][i]
    if (tid < nplanes * 80) {
      const int tl = tid / 80, r = tid - tl * 80;
      const int dg = r / 10, ig = r - dg * 10;
      const int d0 = dg * 4, i0 = ig * 4;
      const float* wg = wsym + (tbase + tl) * 1024;
      float acc[4][4];   // [di][ii]
      #pragma unroll
      for (int a = 0; a < 4; ++a)
        #pragma unroll
        for (int b = 0; b < 4; ++b) acc[a][b] = 0.f;
      #pragma unroll 8
      for (int c = 0; c < 32; ++c) {
        float4 zv = *(const float4*)&S[OFF_ZT + c * 40 + i0];
        float4 wv = *(const float4*)(wg + c * 32 + d0);
        acc[0][0] += wv.x * zv.x; acc[0][1] += wv.x * zv.y; acc[0][2] += wv.x * zv.z; acc[0][3] += wv.x * zv.w;
        acc[1][0] += wv.y * zv.x; acc[1][1] += wv.y * zv.y; acc[1][2] += wv.y * zv.z; acc[1][3] += wv.y * zv.w;
        acc[2][0] += wv.z * zv.x; acc[2][1] += wv.z * zv.y; acc[2][2] += wv.z * zv.z; acc[2][3] += wv.z * zv.w;
        acc[3][0] += wv.w * zv.x; acc[3][1] += wv.w * zv.y; acc[3][2] += wv.w * zv.z; acc[3][3] += wv.w * zv.w;
      }
      #pragma unroll
      for (int a = 0; a < 4; ++a)
        *(float4*)&S[OFF_A + tl * UTP + (d0 + a) * 40 + i0] =
            make_float4(acc[a][0], acc[a][1], acc[a][2], acc[a][3]);
    }
    __syncthreads();

    // bilinear: units (tl, triangular 4i x 4j tile)
    if (tid < nplanes * 55) {
      const int tl = tid / 55;
      int q = tid - tl * 55;
      int ig = 0;
      while (q >= 10 - ig) { q -= 10 - ig; ++ig; }
      const int jg = ig + q;
      const int i0 = ig * 4, j0 = jg * 4;
      float acc[4][4];
      #pragma unroll
      for (int a = 0; a < 4; ++a)
        #pragma unroll
        for (int b = 0; b < 4; ++b) acc[a][b] = 0.f;
      #pragma unroll 8
      for (int d = 0; d < 32; ++d) {
        float4 uv = *(const float4*)&S[OFF_A + tl * UTP + d * 40 + i0];
        float4 zv = *(const float4*)&S[OFF_ZT + d * 40 + j0];
        acc[0][0] += uv.x * zv.x; acc[0][1] += uv.x * zv.y; acc[0][2] += uv.x * zv.z; acc[0][3] += uv.x * zv.w;
        acc[1][0] += uv.y * zv.x; acc[1][1] += uv.y * zv.y; acc[1][2] += uv.y * zv.z; acc[1][3] += uv.y * zv.w;
        acc[2][0] += uv.z * zv.x; acc[2][1] += uv.z * zv.y; acc[2][2] += uv.z * zv.z; acc[2][3] += uv.z * zv.w;
        acc[3][0] += uv.w * zv.x; acc[3][1] += uv.w * zv.y; acc[3][2] += uv.w * zv.z; acc[3][3] += uv.w * zv.w;
      }
      const int tg = tbase + tl;
      #pragma unroll
      for (int a = 0; a < 4; ++a) {
        const int i = i0 + a;
        #pragma unroll
        for (int b = 0; b < 4; ++b) {
          const int j = j0 + b;
          if (i < j) {
            const int p = i * (79 - i) / 2 + (j - i - 1);
            S[OFF_BT + tg * 780 + p] = acc[a][b];
          }
        }
      }
    }
    __syncthreads();
  }

  // ---------- phase 8: edge head; weights via UNIFORM global loads (s_load) ----------
  const float* w1h = hwg;
  const float* b1h = hwg + 320;
  const float* w2t = hwg + 384;
  const float* b2h = hwg + 704;
  const float* wsh = hwg + 709;
  const float* bsh = hwg + 734;

  // main: 3 unconditional slots (pairs 0..767)
  float bil5[3][5], lg[3][5];
  #pragma unroll
  for (int s = 0; s < 3; ++s) {
    const int p = tid + (s << 8);
    #pragma unroll
    for (int t = 0; t < 5; ++t) bil5[s][t] = S[OFF_BT + t * 780 + p];
    #pragma unroll
    for (int t2 = 0; t2 < 5; ++t2) {
      float a = b2h[t2] + bsh[t2];
      #pragma unroll
      for (int t = 0; t < 5; ++t) a += bil5[s][t] * wsh[t * 5 + t2];
      lg[s][t2] = a;
    }
  }
  for (int j4 = 0; j4 < 16; ++j4) {
    float4 bb = ((const float4*)b1h)[j4];
    float4 h[3];
    #pragma unroll
    for (int s = 0; s < 3; ++s) h[s] = bb;
    #pragma unroll
    for (int t = 0; t < 5; ++t) {
      float4 w1 = ((const float4*)(w1h + t * 64))[j4];
      #pragma unroll
      for (int s = 0; s < 3; ++s) {
        float bt = bil5[s][t];
        h[s].x += bt * w1.x; h[s].y += bt * w1.y; h[s].z += bt * w1.z; h[s].w += bt * w1.w;
      }
    }
    #pragma unroll
    for (int s = 0; s < 3; ++s) {
      h[s].x = fmaxf(h[s].x, 0.f); h[s].y = fmaxf(h[s].y, 0.f);
      h[s].z = fmaxf(h[s].z, 0.f); h[s].w = fmaxf(h[s].w, 0.f);
    }
    #pragma unroll
    for (int t2 = 0; t2 < 5; ++t2) {
      float4 w2 = ((const float4*)(w2t + t2 * 64))[j4];
      #pragma unroll
      for (int s = 0; s < 3; ++s)
        lg[s][t2] += h[s].x * w2.x + h[s].y * w2.y + h[s].z * w2.z + h[s].w * w2.w;
    }
  }
  #pragma unroll
  for (int s = 0; s < 3; ++s) {
    const int p = tid + (s << 8);
    float mx = lg[s][0];
    #pragma unroll
    for (int t2 = 1; t2 < 5; ++t2) mx = fmaxf(mx, lg[s][t2]);
    float e[5], sum = 0.f;
    #pragma unroll
    for (int t2 = 0; t2 < 5; ++t2) { e[t2] = __expf(lg[s][t2] - mx); sum += e[t2]; }
    float inv = 1.f / sum;
    float* outp = edge_out + ((size_t)m * NPAIR + p) * 5;
    #pragma unroll
    for (int t2 = 0; t2 < 5; ++t2) outp[t2] = e[t2] * inv;
  }

  // tail: pairs 768..779 on wave 0
  if (tid < 12) {
    const int p = 768 + tid;
    float bt[5], lgt[5];
    #pragma unroll
    for (int t = 0; t < 5; ++t) bt[t] = S[OFF_BT + t * 780 + p];
    #pragma unroll
    for (int t2 = 0; t2 < 5; ++t2) {
      float a = b2h[t2] + bsh[t2];
      #pragma unroll
      for (int t = 0; t < 5; ++t) a += bt[t] * wsh[t * 5 + t2];
      lgt[t2] = a;
    }
    for (int j = 0; j < 64; ++j) {
      float hv = b1h[j];
      #pragma unroll
      for (int t = 0; t < 5; ++t) hv += bt[t] * w1h[t * 64 + j];
      hv = fmaxf(hv, 0.f);
      #pragma unroll
      for (int t2 = 0; t2 < 5; ++t2) lgt[t2] += hv * w2t[t2 * 64 + j];
    }
    float mx = lgt[0];
    #pragma unroll
    for (int t2 = 1; t2 < 5; ++t2) mx = fmaxf(mx, lgt[t2]);
    float e[5], sum = 0.f;
    #pragma unroll
    for (int t2 = 0; t2 < 5; ++t2) { e[t2] = __expf(lgt[t2] - mx); sum += e[t2]; }
    float inv = 1.f / sum;
    float* outp = edge_out + ((size_t)m * NPAIR + p) * 5;
    #pragma unroll
    for (int t2 = 0; t2 < 5; ++t2) outp[t2] = e[t2] * inv;
  }
}

extern "C" void kernel_launch(void* const* d_in, const int* in_sizes, int n_in,
                              void* d_out, int out_size, void* d_ws, size_t ws_size,
                              hipStream_t stream) {
  const float* eta    = (const float*)d_in[0];
  const float* gumbel = (const float*)d_in[1];
  const float* z_noise= (const float*)d_in[2];
  const float* cW1 = (const float*)d_in[3];
  const float* cb1 = (const float*)d_in[4];
  const float* cW2 = (const float*)d_in[5];
  const float* cb2 = (const float*)d_in[6];
  const float* cWs = (const float*)d_in[7];
  const float* cbs = (const float*)d_in[8];
  const float* means = (const float*)d_in[9];
  const float* lsig  = (const float*)d_in[10];
  const float* aW1 = (const float*)d_in[11];
  const float* ab1 = (const float*)d_in[12];
  const float* aW2 = (const float*)d_in[13];
  const float* ab2 = (const float*)d_in[14];
  const float* aWs = (const float*)d_in[15];
  const float* abs_= (const float*)d_in[16];
  const float* bond= (const float*)d_in[17];
  const float* bW1 = (const float*)d_in[18];
  const float* bb1 = (const float*)d_in[19];
  const float* bW2 = (const float*)d_in[20];
  const float* bb2 = (const float*)d_in[21];
  const float* bWs = (const float*)d_in[22];
  const float* bbs = (const float*)d_in[23];

  float* wsym   = (float*)d_ws;          // 5120
  float* sigma  = wsym + 5120;           // 1024
  float* hwg    = sigma + 1024;          // 744 (+pad)
  float* log_pi = hwg + 768;             // 1024*32
  float* atom_out = (float*)d_out;                    // 1024*400
  float* edge_out = atom_out + (size_t)1024 * 400;    // 1024*780*5

  prep_kernel<<<284, 256, 0, stream>>>(eta, cW1, cb1, cW2, cb2, cWs, cbs,
                                       bond, lsig, bW1, bb1, bW2, bb2, bWs, bbs,
                                       log_pi, wsym, sigma, hwg);
  fused_kernel<<<1024, 256, 0, stream>>>(log_pi, gumbel, z_noise,
                                         means, sigma, aW1, ab1, aW2, ab2, aWs, abs_,
                                         wsym, hwg, atom_out, edge_out);
}